// Round 3
// baseline (1906.955 us; speedup 1.0000x reference)
//
#include <hip/hip_runtime.h>
#include <hip/hip_bf16.h>
#include <cstdint>

#define B_    32
#define NPIX  4096

// ---- workspace layout (floats) ----
#define N_MULTI   ((size_t)B_*288*NPIX)                 // qkv | m3 | m5   (B,288,4096)
#define OFF_ATT   (N_MULTI)
#define N_ATT     ((size_t)B_*96*NPIX)                  // (B,96,4096)
#define OFF_PWS   (OFF_ATT + N_ATT)
#define N_PWS     (960*96)
#define OFF_PB    (OFF_PWS + N_PWS)
#define OFF_VKP   (OFF_PB + 960)                        // B*12*4*72 partial vk sums

#define OFF_O2    ((size_t)B_*NPIX*192)
#define OFF_O3    (OFF_O2 + (size_t)B_*NPIX*256)

// ---------------- K0: fold BN into proj weights ----------------
__global__ void k_prep(const float* __restrict__ proj_w, const float* __restrict__ bn_g,
                       const float* __restrict__ bn_b, const float* __restrict__ bn_m,
                       const float* __restrict__ bn_v, float* __restrict__ pws,
                       float* __restrict__ pbias){
  int idx = blockIdx.x*256 + threadIdx.x;
  if (idx < 960*96){
    int o = idx / 96;
    float sc = bn_g[o] * rsqrtf(bn_v[o] + 1e-5f);
    pws[idx] = proj_w[idx] * sc;
  }
  if (idx < 960){
    float sc = bn_g[idx] * rsqrtf(bn_v[idx] + 1e-5f);
    pbias[idx] = bn_b[idx] - bn_m[idx] * sc;
  }
}

// ---------------- K1: LN(stats+apply) fused QKV GEMM -> multi[:,0:96,:] ----------------
// tile: 128 rows(n) x 96 outs, KC=32. 256 thr: og=t&15 (6 outs), rg=t>>4 (8 rows)
__launch_bounds__(256)
__global__ void k_lnqkv(const float* __restrict__ x1, const float* __restrict__ x2,
                        const float* __restrict__ x3,
                        const float* __restrict__ g1, const float* __restrict__ b1,
                        const float* __restrict__ g2, const float* __restrict__ b2,
                        const float* __restrict__ g3, const float* __restrict__ b3,
                        const float* __restrict__ qkv_w, float* __restrict__ multi){
  __shared__ float xs[32][136];    // [k][row 0..127]
  __shared__ float wsk[32][100];   // [k][o]
  __shared__ float gl[960], bl[960];
  __shared__ float st[128][6];
  int t = threadIdx.x;
  int b  = blockIdx.x >> 5;
  int n0 = (blockIdx.x & 31) << 7;

  for (int i = t; i < 960; i += 256){
    float g, bb;
    if (i < 192){ g = g1[i];      bb = b1[i]; }
    else if (i < 448){ g = g2[i-192]; bb = b2[i-192]; }
    else { g = g3[i-448]; bb = b3[i-448]; }
    gl[i] = g; bl[i] = bb;
  }

  // pass A: per-row LN stats for the block's 128 rows (wave-per-row, 32 rows/wave)
  int lane = t & 63, wv = t >> 6;
  for (int r = wv; r < 128; r += 4){
    size_t rowb = (size_t)(b*NPIX + n0 + r);
    const float* p1 = x1 + rowb*192;
    const float* p2 = x2 + rowb*256;
    const float* p3 = x3 + rowb*512;
    float s0=0.f,q0=0.f, s1=0.f,q1=0.f, s2=0.f,q2=0.f;
    #pragma unroll
    for (int i = 0; i < 3; ++i){ float v = p1[i*64+lane]; s0 += v; q0 = fmaf(v,v,q0); }
    #pragma unroll
    for (int i = 0; i < 4; ++i){ float v = p2[i*64+lane]; s1 += v; q1 = fmaf(v,v,q1); }
    #pragma unroll
    for (int i = 0; i < 8; ++i){ float v = p3[i*64+lane]; s2 += v; q2 = fmaf(v,v,q2); }
    #pragma unroll
    for (int off = 32; off; off >>= 1){
      s0 += __shfl_xor(s0,off); q0 += __shfl_xor(q0,off);
      s1 += __shfl_xor(s1,off); q1 += __shfl_xor(q1,off);
      s2 += __shfl_xor(s2,off); q2 += __shfl_xor(q2,off);
    }
    if (lane == 0){
      float mu0 = s0*(1.f/192.f); st[r][0]=mu0; st[r][1]=rsqrtf(q0*(1.f/192.f)-mu0*mu0+1e-6f);
      float mu1 = s1*(1.f/256.f); st[r][2]=mu1; st[r][3]=rsqrtf(q1*(1.f/256.f)-mu1*mu1+1e-6f);
      float mu2 = s2*(1.f/512.f); st[r][4]=mu2; st[r][5]=rsqrtf(q2*(1.f/512.f)-mu2*mu2+1e-6f);
    }
  }
  __syncthreads();

  int og = t & 15, rg = t >> 4;
  float acc[8][6];
  #pragma unroll
  for (int i = 0; i < 8; ++i)
    for (int j = 0; j < 6; ++j) acc[i][j] = 0.f;

  int srow = t >> 1;   // 0..127
  int sj   = t & 1;    // 16-col half of the 32-k chunk
  for (int k0 = 0; k0 < 960; k0 += 32){
    // stage x (normalized on load); rows L2-hot from pass A
    int seg = (k0 >= 192) + (k0 >= 448);
    const float* xp; int cw, co;
    if (seg == 0){ xp = x1; cw = 192; co = 0; }
    else if (seg == 1){ xp = x2; cw = 256; co = 192; }
    else { xp = x3; cw = 512; co = 448; }
    const float* rp = xp + ((size_t)(b*NPIX + n0 + srow))*cw + (k0 - co) + sj*16;
    float4 a0 = *(const float4*)(rp);
    float4 a1 = *(const float4*)(rp + 4);
    float4 a2 = *(const float4*)(rp + 8);
    float4 a3 = *(const float4*)(rp + 12);
    float mu = st[srow][seg*2], rs = st[srow][seg*2+1];
    int cb = k0 + sj*16;
    float vals[16] = {a0.x,a0.y,a0.z,a0.w, a1.x,a1.y,a1.z,a1.w,
                      a2.x,a2.y,a2.z,a2.w, a3.x,a3.y,a3.z,a3.w};
    #pragma unroll
    for (int m = 0; m < 16; ++m){
      float ga = rs * gl[cb+m];
      xs[sj*16+m][srow] = fmaf(vals[m]-mu, ga, bl[cb+m]);
    }
    // stage w
    #pragma unroll
    for (int i = 0; i < 3; ++i){
      int e = t + i*256;                  // 0..767
      int o = e >> 3, kq = e & 7;         // o 0..95, k = kq*4
      float4 w4 = *(const float4*)&qkv_w[(size_t)o*960 + k0 + kq*4];
      wsk[kq*4+0][o] = w4.x; wsk[kq*4+1][o] = w4.y;
      wsk[kq*4+2][o] = w4.z; wsk[kq*4+3][o] = w4.w;
    }
    __syncthreads();
    #pragma unroll
    for (int k = 0; k < 32; ++k){
      float4 xv0 = *(const float4*)&xs[k][rg*8];
      float4 xv1 = *(const float4*)&xs[k][rg*8+4];
      const float2* wp = (const float2*)&wsk[k][og*6];
      float2 w0 = wp[0], w1 = wp[1], w2 = wp[2];
      float xa[8] = {xv0.x,xv0.y,xv0.z,xv0.w, xv1.x,xv1.y,xv1.z,xv1.w};
      float wa[6] = {w0.x,w0.y, w1.x,w1.y, w2.x,w2.y};
      #pragma unroll
      for (int i = 0; i < 8; ++i)
        for (int j = 0; j < 6; ++j) acc[i][j] = fmaf(xa[i], wa[j], acc[i][j]);
    }
    __syncthreads();
  }
  #pragma unroll
  for (int j = 0; j < 6; ++j){
    int o = og*6 + j;
    float* mp = &multi[((size_t)b*288 + o)*NPIX + n0 + rg*8];
    *(float4*)mp       = make_float4(acc[0][j], acc[1][j], acc[2][j], acc[3][j]);
    *(float4*)(mp + 4) = make_float4(acc[4][j], acc[5][j], acc[6][j], acc[7][j]);
  }
}

// ---------------- K2: fused depthwise + grouped pointwise ----------------
template<int KS>
__launch_bounds__(256)
__global__ void k_conv(const float* __restrict__ dw_w, const float* __restrict__ pw_w,
                       float* __restrict__ multi, int cbase){
  constexpr int R  = KS/2;
  constexpr int TW = 32 + 2*R;
  __shared__ float in_t[8][TW][TW];
  __shared__ float dws[8*KS*KS];
  __shared__ float pwS[64];
  int t   = threadIdx.x;
  int blk = blockIdx.x;
  int b    = blk / 48;
  int rem  = blk % 48;
  int g    = rem >> 2;
  int tile = rem & 3;
  int y0 = (tile >> 1)*32, x0 = (tile & 1)*32;
  const float* src = multi + (size_t)b*288*NPIX + (size_t)g*8*NPIX;
  for (int idx = t; idx < 8*TW*TW; idx += 256){
    int i  = idx / (TW*TW);
    int r2 = idx % (TW*TW);
    int ly = r2 / TW, lx = r2 % TW;
    int gy = y0 + ly - R, gx = x0 + lx - R;
    float v = 0.f;
    if (gy >= 0 && gy < 64 && gx >= 0 && gx < 64) v = src[(size_t)i*NPIX + gy*64 + gx];
    in_t[i][ly][lx] = v;
  }
  if (t < 8*KS*KS) dws[t] = dw_w[(g*8 + t/(KS*KS))*(KS*KS) + t%(KS*KS)];
  if (t < 64)      pwS[t] = pw_w[(g*8 + (t>>3))*8 + (t&7)];
  __syncthreads();
  float* dst = multi + ((size_t)b*288 + cbase + g*8)*NPIX;
  #pragma unroll
  for (int pp = 0; pp < 4; ++pp){
    int p  = t + pp*256;
    int py = p >> 5, px = p & 31;
    float dwv[8];
    #pragma unroll
    for (int i = 0; i < 8; ++i){
      float s = 0.f;
      #pragma unroll
      for (int ky = 0; ky < KS; ++ky){
        #pragma unroll
        for (int kx = 0; kx < KS; ++kx)
          s = fmaf(in_t[i][py+ky][px+kx], dws[i*KS*KS + ky*KS + kx], s);
      }
      dwv[i] = s;
    }
    int sp = (y0 + py)*64 + x0 + px;
    #pragma unroll
    for (int o = 0; o < 8; ++o){
      float s = 0.f;
      #pragma unroll
      for (int i = 0; i < 8; ++i) s = fmaf(dwv[i], pwS[o*8+i], s);
      dst[(size_t)o*NPIX + sp] = s;
    }
  }
}

// ---------------- K3a: linear attention, vk partial sums per n-chunk ----------------
__launch_bounds__(256)
__global__ void k_attn1(const float* __restrict__ multi, float* __restrict__ vkp){
  int t = threadIdx.x;
  int chunk = blockIdx.x & 3;
  int g = (blockIdx.x >> 2) % 12;
  int b = blockIdx.x / 48;
  const float* base = multi + ((size_t)b*288 + g*24)*NPIX + chunk*1024 + t*4;
  float4 kv4[8], vv4[8];
  #pragma unroll
  for (int e = 0; e < 8; ++e){
    float4 v = *(const float4*)(base + (size_t)(8+e)*NPIX);
    kv4[e] = make_float4(fmaxf(v.x,0.f), fmaxf(v.y,0.f), fmaxf(v.z,0.f), fmaxf(v.w,0.f));
  }
  #pragma unroll
  for (int d = 0; d < 8; ++d) vv4[d] = *(const float4*)(base + (size_t)(16+d)*NPIX);

  float acc[72];
  #pragma unroll
  for (int d = 0; d < 8; ++d){
    #pragma unroll
    for (int e = 0; e < 8; ++e){
      float s;
      s = vv4[d].x * kv4[e].x;
      s = fmaf(vv4[d].y, kv4[e].y, s);
      s = fmaf(vv4[d].z, kv4[e].z, s);
      s = fmaf(vv4[d].w, kv4[e].w, s);
      acc[d*8+e] = s;
    }
  }
  #pragma unroll
  for (int e = 0; e < 8; ++e) acc[64+e] = kv4[e].x + kv4[e].y + kv4[e].z + kv4[e].w;

  __shared__ float red[4][72];
  int lane = t & 63, wv = t >> 6;
  #pragma unroll
  for (int m = 0; m < 72; ++m){
    float v = acc[m];
    #pragma unroll
    for (int off = 32; off; off >>= 1) v += __shfl_down(v, off);
    if (lane == 0) red[wv][m] = v;
  }
  __syncthreads();
  if (t < 72) vkp[(size_t)blockIdx.x*72 + t] = red[0][t] + red[1][t] + red[2][t] + red[3][t];
}

// ---------------- K3b: apply vk to q -> att ----------------
__launch_bounds__(256)
__global__ void k_attn2(const float* __restrict__ multi, const float* __restrict__ vkp,
                        float* __restrict__ att){
  int t = threadIdx.x;
  int chunk = blockIdx.x & 3;
  int g = (blockIdx.x >> 2) % 12;
  int b = blockIdx.x / 48;
  __shared__ float vks[72];
  if (t < 72){
    const float* vp = vkp + ((size_t)(b*48 + g*4))*72 + t;
    vks[t] = vp[0] + vp[72] + vp[144] + vp[216];
  }
  __syncthreads();
  const float* base = multi + ((size_t)b*288 + g*24)*NPIX + chunk*1024 + t*4;
  float* ab = att + ((size_t)b*96 + g*8)*NPIX + chunk*1024 + t*4;
  float4 qv4[8];
  #pragma unroll
  for (int e = 0; e < 8; ++e){
    float4 v = *(const float4*)(base + (size_t)e*NPIX);
    qv4[e] = make_float4(fmaxf(v.x,0.f), fmaxf(v.y,0.f), fmaxf(v.z,0.f), fmaxf(v.w,0.f));
  }
  float4 den = make_float4(0.f,0.f,0.f,0.f);
  #pragma unroll
  for (int e = 0; e < 8; ++e){
    float c = vks[64+e];
    den.x = fmaf(c, qv4[e].x, den.x); den.y = fmaf(c, qv4[e].y, den.y);
    den.z = fmaf(c, qv4[e].z, den.z); den.w = fmaf(c, qv4[e].w, den.w);
  }
  float4 rd = make_float4(1.f/(den.x+1e-15f), 1.f/(den.y+1e-15f),
                          1.f/(den.z+1e-15f), 1.f/(den.w+1e-15f));
  #pragma unroll
  for (int d = 0; d < 8; ++d){
    float4 num = make_float4(0.f,0.f,0.f,0.f);
    #pragma unroll
    for (int e = 0; e < 8; ++e){
      float c = vks[d*8+e];
      num.x = fmaf(c, qv4[e].x, num.x); num.y = fmaf(c, qv4[e].y, num.y);
      num.z = fmaf(c, qv4[e].z, num.z); num.w = fmaf(c, qv4[e].w, num.w);
    }
    *(float4*)(ab + (size_t)d*NPIX) =
      make_float4(num.x*rd.x, num.y*rd.y, num.z*rd.z, num.w*rd.w);
  }
}

// ---------------- K4: proj GEMM + BN + residual + split outputs ----------------
// tile: 128 rows x 96 outs (of 960), direct float2 residual-RMW epilogue
__launch_bounds__(256)
__global__ void k_proj(const float* __restrict__ att, const float* __restrict__ pws,
                       const float* __restrict__ pbias,
                       const float* __restrict__ x1, const float* __restrict__ x2,
                       const float* __restrict__ x3, float* __restrict__ out){
  __shared__ float xs[32][136];
  __shared__ float wsk[32][100];
  int t = threadIdx.x;
  int tile = blockIdx.x / 10;
  int oc0  = (blockIdx.x % 10)*96;
  int b  = tile >> 5;
  int n0 = (tile & 31) << 7;
  int og = t & 15, rg = t >> 4;
  float acc[8][6];
  #pragma unroll
  for (int i = 0; i < 8; ++i)
    for (int j = 0; j < 6; ++j) acc[i][j] = 0.f;

  int srow8 = t >> 5;        // 0..7
  int scol  = (t & 31) * 4;  // 0..124
  for (int k0 = 0; k0 < 96; k0 += 32){
    #pragma unroll
    for (int q = 0; q < 4; ++q){
      int kr = q*8 + srow8;
      float4 v = *(const float4*)&att[((size_t)b*96 + k0 + kr)*NPIX + n0 + scol];
      *(float4*)&xs[kr][scol] = v;
    }
    #pragma unroll
    for (int i = 0; i < 3; ++i){
      int e = t + i*256;
      int o = e >> 3, kq = e & 7;
      float4 w4 = *(const float4*)&pws[(size_t)(oc0 + o)*96 + k0 + kq*4];
      wsk[kq*4+0][o] = w4.x; wsk[kq*4+1][o] = w4.y;
      wsk[kq*4+2][o] = w4.z; wsk[kq*4+3][o] = w4.w;
    }
    __syncthreads();
    #pragma unroll
    for (int k = 0; k < 32; ++k){
      float4 xv0 = *(const float4*)&xs[k][rg*8];
      float4 xv1 = *(const float4*)&xs[k][rg*8+4];
      const float2* wp = (const float2*)&wsk[k][og*6];
      float2 w0 = wp[0], w1 = wp[1], w2 = wp[2];
      float xa[8] = {xv0.x,xv0.y,xv0.z,xv0.w, xv1.x,xv1.y,xv1.z,xv1.w};
      float wa[6] = {w0.x,w0.y, w1.x,w1.y, w2.x,w2.y};
      #pragma unroll
      for (int i = 0; i < 8; ++i)
        for (int j = 0; j < 6; ++j) acc[i][j] = fmaf(xa[i], wa[j], acc[i][j]);
    }
    __syncthreads();
  }

  float pb[6];
  #pragma unroll
  for (int j = 0; j < 6; ++j) pb[j] = pbias[oc0 + og*6 + j];

  #pragma unroll
  for (int i = 0; i < 8; ++i){
    size_t rowb = (size_t)b*NPIX + (n0 + rg*8 + i);
    #pragma unroll
    for (int j = 0; j < 6; j += 2){
      int o = oc0 + og*6 + j;
      float vx = acc[i][j]   + pb[j];
      float vy = acc[i][j+1] + pb[j+1];
      const float* xr; float* op;
      if (o < 192){
        size_t idx = rowb*192 + o;        xr = x1 + idx; op = out + idx;
      } else if (o < 448){
        size_t idx = rowb*256 + (o-192);  xr = x2 + idx; op = out + OFF_O2 + idx;
      } else {
        size_t idx = rowb*512 + (o-448);  xr = x3 + idx; op = out + OFF_O3 + idx;
      }
      float2 r = *(const float2*)xr;
      float2 v = make_float2(vx + r.x, vy + r.y);
      *(float2*)op = v;
    }
  }
}

extern "C" void kernel_launch(void* const* d_in, const int* in_sizes, int n_in,
                              void* d_out, int out_size, void* d_ws, size_t ws_size,
                              hipStream_t stream){
  const float* x1    = (const float*)d_in[0];
  const float* g1    = (const float*)d_in[1];
  const float* b1    = (const float*)d_in[2];
  const float* x2    = (const float*)d_in[3];
  const float* g2    = (const float*)d_in[4];
  const float* b2    = (const float*)d_in[5];
  const float* x3    = (const float*)d_in[6];
  const float* g3    = (const float*)d_in[7];
  const float* b3    = (const float*)d_in[8];
  const float* qkv_w = (const float*)d_in[9];
  const float* dw3_w = (const float*)d_in[10];
  const float* pw3_w = (const float*)d_in[11];
  const float* dw5_w = (const float*)d_in[12];
  const float* pw5_w = (const float*)d_in[13];
  const float* proj_w= (const float*)d_in[14];
  const float* bn_g  = (const float*)d_in[15];
  const float* bn_b  = (const float*)d_in[16];
  const float* bn_m  = (const float*)d_in[17];
  const float* bn_v  = (const float*)d_in[18];

  float* ws    = (float*)d_ws;
  float* multi = ws;
  float* attb  = ws + OFF_ATT;
  float* pws   = ws + OFF_PWS;
  float* pbias = ws + OFF_PB;
  float* vkp   = ws + OFF_VKP;
  float* out   = (float*)d_out;

  k_prep  <<<360, 256, 0, stream>>>(proj_w, bn_g, bn_b, bn_m, bn_v, pws, pbias);
  k_lnqkv <<<B_*32, 256, 0, stream>>>(x1,x2,x3,g1,b1,g2,b2,g3,b3,qkv_w,multi);
  k_conv<3><<<B_*48, 256, 0, stream>>>(dw3_w, pw3_w, multi, 96);
  k_conv<5><<<B_*48, 256, 0, stream>>>(dw5_w, pw5_w, multi, 192);
  k_attn1 <<<B_*48, 256, 0, stream>>>(multi, vkp);
  k_attn2 <<<B_*48, 256, 0, stream>>>(multi, vkp, attb);
  k_proj  <<<(B_*32)*10, 256, 0, stream>>>(attb, pws, pbias, x1, x2, x3, out);
}